// Round 7
// baseline (477.818 us; speedup 1.0000x reference)
//
#include <hip/hip_runtime.h>
#include <math.h>

// Problem constants (reference: VOCAB=10000, HID=256, B=64, T=64)
#define VOCABN 10000
#define HIDN   256
#define GATES  1024   // 4*HID
#define BN     64
#define TN     64
#define BT     4096   // B*T
#define NCT    625    // vocab col-tiles of 16 (10000 = 625*16 exactly)

typedef unsigned int       u32;
typedef unsigned short     u16;
typedef unsigned long long u64;
typedef float v4f __attribute__((ext_vector_type(4)));
typedef short v8s __attribute__((ext_vector_type(8)));

#define SENT 0xFFFFFFFFFFFFFFFFull   // 4x bf16 -NaN: never a legal h pack

__device__ __forceinline__ float bf2f(u16 u) {
    return __uint_as_float(((u32)u) << 16);
}
__device__ __forceinline__ u16 f2bf(float f) {          // round-to-nearest-even
    u32 u = __float_as_uint(f);
    u += 0x7FFFu + ((u >> 16) & 1u);
    return (u16)(u >> 16);
}
__device__ __forceinline__ float fast_sigmoid(float x) {
    return 1.0f / (1.0f + __expf(-x));
}
__device__ __forceinline__ float fast_tanh(float x) {
    float e = __expf(-2.0f * fabsf(x));
    float t = (1.0f - e) / (1.0f + e);
    return copysignf(t, x);
}
__device__ __forceinline__ u64 llc_load(const u64* p) {
    return __hip_atomic_load(p, __ATOMIC_RELAXED, __HIP_MEMORY_SCOPE_AGENT);
}
__device__ __forceinline__ void llc_store(u64* p, u64 v) {
    __hip_atomic_store(p, v, __ATOMIC_RELAXED, __HIP_MEMORY_SCOPE_AGENT);
}

// ---------------------------------------------------------------------------
// fp32 [HIDN][ncols] tile c -> bf16 MFMA B-fragment layout [c][8 q][64 l][8].
// Fragment (c,q), lane l holds B[k = q*32 + (l>>4)*8 + j][n = c*16 + (l&15)].
// ---------------------------------------------------------------------------
__device__ __forceinline__ void wfrag_dev(
    const float* __restrict__ src, u16* __restrict__ dst, int ncols, int c,
    int t, u16 lt[HIDN][16])
{
    const float* s = src + (size_t)t * ncols + c * 16;
    #pragma unroll
    for (int j4 = 0; j4 < 4; ++j4) {
        float4 v = *(const float4*)(s + j4 * 4);
        lt[t][j4*4+0] = f2bf(v.x);
        lt[t][j4*4+1] = f2bf(v.y);
        lt[t][j4*4+2] = f2bf(v.z);
        lt[t][j4*4+3] = f2bf(v.w);
    }
    __syncthreads();
    #pragma unroll
    for (int h = 0; h < 2; ++h) {
        int f = t + h * 256;             // frag id = q*64 + l
        int q = f >> 6, l = f & 63;
        int m = l & 15, kb = q * 32 + ((l >> 4) & 3) * 8;
        u32 w[4];
        #pragma unroll
        for (int j = 0; j < 4; ++j)
            w[j] = (u32)lt[kb + 2*j][m] | ((u32)lt[kb + 2*j + 1][m] << 16);
        *(uint4*)(dst + (((size_t)c * 8 + q) * 64 + l) * 8) =
            make_uint4(w[0], w[1], w[2], w[3]);
    }
}

// ---------------------------------------------------------------------------
// Prep 1: both W_lstm halves -> B-frag layout. 128 blocks.
// ---------------------------------------------------------------------------
__global__ __launch_bounds__(256) void k_prep1(
    const float* __restrict__ W_lstm,
    u16* __restrict__ Wxf, u16* __restrict__ Whf)
{
    __shared__ u16 lt[HIDN][16];
    const int bid = blockIdx.x;
    if (bid < 64)
        wfrag_dev(W_lstm, Wxf, GATES, bid, threadIdx.x, lt);
    else
        wfrag_dev(W_lstm + (size_t)HIDN * GATES, Whf, GATES, bid - 64,
                  threadIdx.x, lt);
}

// ---------------------------------------------------------------------------
// Prep 2 (fused): blocks 0..624 transform W_dense -> Wf; blocks 625..880 run
// xgates: gates_x = E[idx] @ W_x + b_lstm -> bf16.
// ---------------------------------------------------------------------------
__global__ __launch_bounds__(256) void k_prep2(
    const float* __restrict__ W_dense,
    const int*   __restrict__ idx,   // [BT]
    const float* __restrict__ E,     // [VOCAB][HIDN]
    const u16*   __restrict__ Wxf,   // [64][8][64][8]
    const float* __restrict__ bl,    // [GATES]
    u16*         __restrict__ Wf,    // [625][8][64][8]
    u16*         __restrict__ gxb)   // [BT][GATES] bf16
{
    __shared__ u16 lt[HIDN][16];
    const int bid = blockIdx.x;
    const int tid = threadIdx.x;
    if (bid < NCT) {
        wfrag_dev(W_dense, Wf, VOCABN, bid, tid, lt);
        return;
    }
    const int r0   = (bid - NCT) * 16;
    const int w    = tid >> 6, lane = tid & 63;
    const int m    = lane & 15, quad = lane >> 4;

    v8s a[8];
    {
        const float* e = E + (size_t)idx[r0 + m] * HIDN + quad * 8;
        #pragma unroll
        for (int q = 0; q < 8; ++q) {
            float4 x0 = *(const float4*)(e + q * 32);
            float4 x1 = *(const float4*)(e + q * 32 + 4);
            uint4 t4 = make_uint4(
                (u32)f2bf(x0.x) | ((u32)f2bf(x0.y) << 16),
                (u32)f2bf(x0.z) | ((u32)f2bf(x0.w) << 16),
                (u32)f2bf(x1.x) | ((u32)f2bf(x1.y) << 16),
                (u32)f2bf(x1.z) | ((u32)f2bf(x1.w) << 16));
            a[q] = *(v8s*)&t4;
        }
    }
    for (int c = w; c < GATES / 16; c += 4) {
        v4f acc = {0.f, 0.f, 0.f, 0.f};
        #pragma unroll
        for (int q = 0; q < 8; ++q) {
            v8s b = *(const v8s*)(Wxf + (((size_t)c * 8 + q) * 64 + lane) * 8);
            acc = __builtin_amdgcn_mfma_f32_16x16x32_bf16(a[q], b, acc, 0, 0, 0);
        }
        const int col = c * 16 + m;
        const float bv = bl[col];
        #pragma unroll
        for (int r = 0; r < 4; ++r)   // D: col=lane&15, row=quad*4+r (m89/m91)
            gxb[(size_t)(r0 + quad * 4 + r) * GATES + col] = f2bf(acc[r] + bv);
    }
}

// ---------------------------------------------------------------------------
// MEGA kernel, 160 blocks:
//   blocks 0..31  : persistent MFMA LSTM (4 row-groups x 8 unit-slices),
//                   W_h slice LDS-resident, h published per step to the
//                   LLC exchange Hx[t] (sentinel-initialized) via relaxed
//                   agent u64 stores; consumers poll the data words.
//   blocks 32..159: dense+softmax, one block per (t, batch-half): polls its
//                   32 rows of Hx[t] (cheap probe + s_sleep), sweeps the
//                   whole vocab with MFMA, captures target logits in-flight,
//                   writes final perplexities. Runs in the recurrence's
//                   shadow on the otherwise-idle CUs.
// No deadlock: 160 blocks < 256 CUs -> all resident regardless of order.
// ---------------------------------------------------------------------------
__global__ __launch_bounds__(256) void k_mega(
    const u16*   __restrict__ Whf,   // [64 ct][8][64][8] h-part frags
    const u16*   __restrict__ gxb,   // [BT][GATES] bf16
    u16*                      Hx,    // [64][BN][HIDN] bf16, sentinel-filled
    const u16*   __restrict__ Wf,    // [625][8][64][8]
    const float* __restrict__ bd,    // [VOCAB]
    const int*   __restrict__ tgt,   // [B][T]
    float*       __restrict__ out)   // [B][T] perplexity
{
    __shared__ union {
        struct { uint4 Wl4[8 * 512]; float gl[4][16][33]; } p;   // plstm
        struct { float Sl[32]; float tlv[32]; int tg[32]; } d;   // dense
    } sm;

    const int tid  = threadIdx.x;
    const int w    = tid >> 6;
    const int lane = tid & 63;
    const int m    = lane & 15, kq = lane >> 4;   // kq == quad

    if (blockIdx.x < 32) {
        // ================= recurrence role =================
        const int rg = blockIdx.x >> 3;    // row group: batch rows rg*16..+15
        const int ns = blockIdx.x & 7;     // unit slice: units ns*32..+31
        const int u0 = ns * 32;

        {   // W_h slice: tiles ct = g*16 + ns*2 + ut (g=0..3, ut=0..1)
            const uint4* src = (const uint4*)Whf;
            #pragma unroll
            for (int i = 0; i < 16; ++i) {
                int e  = tid + i * 256;
                int tl = e >> 9, off = e & 511;
                int ct = (tl >> 1) * 16 + ns * 2 + (tl & 1);
                sm.p.Wl4[e] = src[(size_t)ct * 512 + off];
            }
        }
        for (int e = tid; e < 4 * 16 * 33; e += 256) ((float*)sm.p.gl)[e] = 0.0f;
        __syncthreads();

        const u16* Wl = (const u16*)sm.p.Wl4;
        const int r = tid >> 4, u = tid & 15;
        const int b = rg * 16 + r;
        const u16* gxp = gxb + (size_t)b * TN * GATES + u0 + u;
        const size_t hxw = (size_t)b * HIDN + u0 + u;
        const size_t arow64 = (size_t)(rg * 16 + m) * (HIDN / 4) + kq * 2;

        float cst0 = 0.0f, cst1 = 0.0f;
        float gr[8], gn[8];
        #pragma unroll
        for (int g = 0; g < 4; ++g) {
            gr[g]     = bf2f(gxp[g * 256]);
            gr[g + 4] = bf2f(gxp[g * 256 + 16]);
        }

        for (int t = 0; t < TN; ++t) {
            if (t + 1 < TN) {
                const u16* p = gxp + (size_t)(t + 1) * GATES;
                #pragma unroll
                for (int g = 0; g < 4; ++g) {
                    gn[g]     = bf2f(p[g * 256]);
                    gn[g + 4] = bf2f(p[g * 256 + 16]);
                }
            }

            if (t > 0) {
                const u64* hb64 = (const u64*)Hx
                    + (size_t)(t - 1) * (BN * HIDN / 4) + arow64;
                u64 d0[8], d1[8];
                bool ok = false;
                while (!ok) {
                    ok = true;
                    #pragma unroll
                    for (int q = 0; q < 8; ++q) {
                        d0[q] = llc_load(hb64 + q * 8);
                        d1[q] = llc_load(hb64 + q * 8 + 1);
                    }
                    #pragma unroll
                    for (int q = 0; q < 8; ++q)
                        if (d0[q] == SENT || d1[q] == SENT) ok = false;
                }
                v4f acc0 = {0.f,0.f,0.f,0.f}, acc1 = {0.f,0.f,0.f,0.f};
                #pragma unroll
                for (int q = 0; q < 8; ++q) {
                    union { u64 d[2]; v8s v; } av;
                    av.d[0] = d0[q]; av.d[1] = d1[q];
                    v8s bf0 = *(const v8s*)(Wl + (((w * 2 + 0) * 8 + q) * 64 + lane) * 8);
                    v8s bf1 = *(const v8s*)(Wl + (((w * 2 + 1) * 8 + q) * 64 + lane) * 8);
                    acc0 = __builtin_amdgcn_mfma_f32_16x16x32_bf16(av.v, bf0, acc0, 0, 0, 0);
                    acc1 = __builtin_amdgcn_mfma_f32_16x16x32_bf16(av.v, bf1, acc1, 0, 0, 0);
                }
                #pragma unroll
                for (int rr = 0; rr < 4; ++rr) {  // row = kq*4+rr, unit = m
                    sm.p.gl[w][kq * 4 + rr][m]      = acc0[rr];
                    sm.p.gl[w][kq * 4 + rr][16 + m] = acc1[rr];
                }
            }
            __syncthreads();

            {
                float ai0 = sm.p.gl[0][r][u]      + gr[0];
                float aj0 = sm.p.gl[1][r][u]      + gr[1];
                float af0 = sm.p.gl[2][r][u]      + gr[2];
                float ao0 = sm.p.gl[3][r][u]      + gr[3];
                float ai1 = sm.p.gl[0][r][u + 16] + gr[4];
                float aj1 = sm.p.gl[1][r][u + 16] + gr[5];
                float af1 = sm.p.gl[2][r][u + 16] + gr[6];
                float ao1 = sm.p.gl[3][r][u + 16] + gr[7];

                float ig0 = fast_sigmoid(ai0), fg0 = fast_sigmoid(af0 + 1.0f);
                float og0 = fast_sigmoid(ao0), jt0 = fast_tanh(aj0);
                cst0 = fg0 * cst0 + ig0 * jt0;
                float hn0 = og0 * fast_tanh(cst0);
                float ig1 = fast_sigmoid(ai1), fg1 = fast_sigmoid(af1 + 1.0f);
                float og1 = fast_sigmoid(ao1), jt1 = fast_tanh(aj1);
                cst1 = fg1 * cst1 + ig1 * jt1;
                float hn1 = og1 * fast_tanh(cst1);

                u32 h0 = f2bf(hn0), h1 = f2bf(hn1);
                u32 a1 = __shfl_down(h0, 1), a2 = __shfl_down(h0, 2), a3 = __shfl_down(h0, 3);
                u32 b1 = __shfl_down(h1, 1), b2 = __shfl_down(h1, 2), b3 = __shfl_down(h1, 3);
                if ((tid & 3) == 0) {
                    u64* dst = (u64*)(Hx + (size_t)t * (BN * HIDN) + hxw);
                    u64 pk0 = (u64)(h0 | (a1 << 16)) | ((u64)(a2 | (a3 << 16)) << 32);
                    u64 pk1 = (u64)(h1 | (b1 << 16)) | ((u64)(b2 | (b3 << 16)) << 32);
                    llc_store(dst,     pk0);
                    llc_store(dst + 4, pk1);
                }
            }

            if (t + 1 < TN) __syncthreads();   // gl reads done before rewrite
            #pragma unroll
            for (int g = 0; g < 8; ++g) gr[g] = gn[g];
        }
        return;
    }

    // ================= dense role =================
    const int d  = blockIdx.x - 32;    // 0..127
    const int tt = d >> 1;             // time step
    const int bh = d & 1;              // batch half: rows bh*32..+31

    if (tid < 32) {
        sm.d.Sl[tid] = 0.0f;
        sm.d.tg[tid] = tgt[(size_t)(bh * 32 + tid) * TN + tt];
    }
    __syncthreads();

    // poll 32 rows (2 a-frag sets) of Hx[tt] at LLC
    const u64* base0 = (const u64*)Hx
        + ((size_t)tt * BN + bh * 32 + m) * (HIDN / 4) + kq * 2;
    const u64* base1 = base0 + 16 * (HIDN / 4);
    // cheap probe first (tiny LLC traffic while waiting)
    while (llc_load(base0) == SENT) __builtin_amdgcn_s_sleep(64);
    v8s a[2][8];
    {
        u64 d00[8], d01[8], d10[8], d11[8];
        bool ok = false;
        while (!ok) {
            ok = true;
            #pragma unroll
            for (int q = 0; q < 8; ++q) {
                d00[q] = llc_load(base0 + q * 8);
                d01[q] = llc_load(base0 + q * 8 + 1);
                d10[q] = llc_load(base1 + q * 8);
                d11[q] = llc_load(base1 + q * 8 + 1);
            }
            #pragma unroll
            for (int q = 0; q < 8; ++q)
                if (d00[q] == SENT || d01[q] == SENT ||
                    d10[q] == SENT || d11[q] == SENT) ok = false;
            if (!ok) __builtin_amdgcn_s_sleep(4);
        }
        #pragma unroll
        for (int q = 0; q < 8; ++q) {
            union { u64 d[2]; v8s v; } av;
            av.d[0] = d00[q]; av.d[1] = d01[q]; a[0][q] = av.v;
            av.d[0] = d10[q]; av.d[1] = d11[q]; a[1][q] = av.v;
        }
    }

    float s[2][4] = {{0.f,0.f,0.f,0.f},{0.f,0.f,0.f,0.f}};
    for (int c = w; c < NCT; c += 4) {
        v4f acc0 = {0.f,0.f,0.f,0.f};
        v4f acc1 = {0.f,0.f,0.f,0.f};
        #pragma unroll
        for (int q = 0; q < 8; ++q) {
            v8s bq = *(const v8s*)(Wf + (((size_t)c * 8 + q) * 64 + lane) * 8);
            acc0 = __builtin_amdgcn_mfma_f32_16x16x32_bf16(a[0][q], bq, acc0, 0, 0, 0);
            acc1 = __builtin_amdgcn_mfma_f32_16x16x32_bf16(a[1][q], bq, acc1, 0, 0, 0);
        }
        const int col = c * 16 + m;
        const float bv = bd[col];
        #pragma unroll
        for (int rt = 0; rt < 2; ++rt) {
            v4f* ac = rt ? &acc1 : &acc0;
            #pragma unroll
            for (int r = 0; r < 4; ++r) {
                float l = (*ac)[r] + bv;
                int row = rt * 16 + kq * 4 + r;       // row within 32
                if (col == sm.d.tg[row]) sm.d.tlv[row] = l;
                s[rt][r] += __expf(l);
            }
        }
    }
    #pragma unroll
    for (int rt = 0; rt < 2; ++rt)
        #pragma unroll
        for (int r = 0; r < 4; ++r)
            atomicAdd(&sm.d.Sl[rt * 16 + kq * 4 + r], s[rt][r]);
    __syncthreads();
    if (tid < 32)
        out[(size_t)(bh * 32 + tid) * TN + tt] =
            __expf(__logf(sm.d.Sl[tid]) - sm.d.tlv[tid]);
}

// ---------------------------------------------------------------------------
extern "C" void kernel_launch(void* const* d_in, const int* in_sizes, int n_in,
                              void* d_out, int out_size, void* d_ws, size_t ws_size,
                              hipStream_t stream) {
    const int*   input   = (const int*)  d_in[0];   // [B,T]
    const int*   targets = (const int*)  d_in[1];   // [B,T]
    const float* E       = (const float*)d_in[2];   // [VOCAB,HID]
    const float* W_lstm  = (const float*)d_in[3];   // [2H,4H]
    const float* b_lstm  = (const float*)d_in[4];   // [4H]
    const float* W_dense = (const float*)d_in[5];   // [HID,VOCAB]
    const float* b_dense = (const float*)d_in[6];   // [VOCAB]
    float* out = (float*)d_out;                     // [B,T] perplexity

    // Workspace (~16.25 MB; 20 MB proven in earlier rounds). NOTE: Wf no
    // longer overlaps gxb — the mega kernel reads both concurrently.
    //  [0,8M):           gxb bf16 [BT][GATES]
    //  [8M,13.12M):      Wf  bf16 [625][8][64][8]
    //  [13.25M,+512K):   Whf (h-part frags)
    //  [13.75M,+512K):   Wxf (x-part frags)
    //  [14.25M,+2M):     Hx bf16 [64][BN][HIDN] sentinel-initialized
    char* ws = (char*)d_ws;
    u16* gxb = (u16*)ws;
    u16* Wf  = (u16*)(ws + ((size_t)8 << 20));
    u16* Whf = (u16*)(ws + ((size_t)13 << 20) + ((size_t)256 << 10));
    u16* Wxf = (u16*)(ws + ((size_t)13 << 20) + ((size_t)768 << 10));
    u16* Hx  = (u16*)(ws + ((size_t)14 << 20) + ((size_t)256 << 10));

    hipMemsetAsync(Hx, 0xFF, (size_t)2 << 20, stream);   // sentinel fill
    k_prep1<<<128,       256, 0, stream>>>(W_lstm, Wxf, Whf);
    k_prep2<<<NCT + 256, 256, 0, stream>>>(W_dense, input, E, Wxf, b_lstm,
                                           Wf, gxb);
    k_mega <<<160,       256, 0, stream>>>(Whf, gxb, Hx, Wf, b_dense,
                                           targets, out);
}